// Round 1
// baseline (7837.603 us; speedup 1.0000x reference)
//
#include <hip/hip_runtime.h>

// LSTM decoder: B=8192, T=128, F=63, H=128, P=64 steps.
// Layout: 256 blocks x 512 threads. Block = 32 batch rows, all 512 gate rows.
// Thread (bl = tid&31, rg = tid>>5) owns j in [rg*8, rg*8+8): h/c regs + 32 gate rows.

#define NB   8192
#define NT   128
#define NF   63
#define NH   128
#define NP   64
#define BB   32
#define NRG  16
#define NJ   8
#define NTHREADS 512

__device__ __forceinline__ float sig_(float v) { return 1.0f / (1.0f + __expf(-v)); }
__device__ __forceinline__ float tanh_(float v) {
    float e = __expf(-2.0f * fabsf(v));
    float t = (1.0f - e) / (1.0f + e);
    return copysignf(t, v);
}

// 4-column FMA block: acc[g][jj] += W[row][col..col+3] * a0..a3, row = g*NH + j0 + jj
__device__ __forceinline__ void fma4(float (&acc)[4][NJ], const float* __restrict__ Wp,
                                     int rstride, int col, int j0,
                                     float a0, float a1, float a2, float a3)
{
    #pragma unroll
    for (int g = 0; g < 4; ++g) {
        #pragma unroll
        for (int jj = 0; jj < NJ; ++jj) {
            const float4 w = *reinterpret_cast<const float4*>(
                &Wp[(size_t)(g * NH + j0 + jj) * rstride + col]);
            float a = acc[g][jj];
            a = fmaf(w.x, a0, a);
            a = fmaf(w.y, a1, a);
            a = fmaf(w.z, a2, a);
            a = fmaf(w.w, a3, a);
            acc[g][jj] = a;
        }
    }
}

__global__ __launch_bounds__(NTHREADS, 2)
void lstm_fused(const float* __restrict__ x, const float* __restrict__ z,
                const float* __restrict__ h0, const float* __restrict__ c0,
                const float* __restrict__ Wih, const float* __restrict__ Whh,
                const float* __restrict__ bih, const float* __restrict__ bhh,
                const float* __restrict__ Wout, const float* __restrict__ bout,
                float* __restrict__ out)
{
    const int tid = threadIdx.x;
    const int bl  = tid & (BB - 1);
    const int rg  = tid >> 5;
    const int j0  = rg * NJ;
    const int bb  = blockIdx.x * BB;
    const int b   = bb + bl;

    __shared__ float s_h[NH][BB];      // h broadcast, bank = bl -> conflict-free
    __shared__ float s_z[BB][65];      // z_t staging, stride 65 -> conflict-free
    __shared__ float s_op[NRG][BB];    // W_out partial sums
    __shared__ float s_ob[NP][BB];     // per-step outputs, flushed at end

    float hreg[NJ], creg[NJ], wo[NJ], bias[4][NJ];

    #pragma unroll
    for (int jj = 0; jj < NJ; ++jj) {
        hreg[jj] = h0[(size_t)b * NH + j0 + jj];
        creg[jj] = c0[(size_t)b * NH + j0 + jj];
        wo[jj]   = Wout[j0 + jj];
    }
    #pragma unroll
    for (int g = 0; g < 4; ++g)
        #pragma unroll
        for (int jj = 0; jj < NJ; ++jj)
            bias[g][jj] = bih[g * NH + j0 + jj] + bhh[g * NH + j0 + jj];

    const float xlast = x[(size_t)b * NT + (NT - 1)];
    const float bo_s  = bout[0];

    // init LDS: h, out-partials, z(t=0)
    {
        float op = 0.f;
        #pragma unroll
        for (int jj = 0; jj < NJ; ++jj) {
            s_h[j0 + jj][bl] = hreg[jj];
            op = fmaf(wo[jj], hreg[jj], op);
        }
        s_op[rg][bl] = op;
    }
    #pragma unroll
    for (int i = 0; i < 4; ++i) {
        int idx = i * NTHREADS + tid;
        if (idx < BB * NF) {
            int bz = idx / NF, f = idx - bz * NF;
            s_z[bz][f] = z[(size_t)(bb + bz) * (NT * NF) + (size_t)(NT - NP) * NF + f];
        }
    }
    __syncthreads();

    for (int t = 0; t < NP; ++t) {
        // T14 split-stage: issue z(t+1) global loads now, LDS-write after barrier
        float zst[4] = {0.f, 0.f, 0.f, 0.f};
        if (t < NP - 1) {
            #pragma unroll
            for (int i = 0; i < 4; ++i) {
                int idx = i * NTHREADS + tid;
                if (idx < BB * NF) {
                    int bz = idx / NF, f = idx - bz * NF;
                    zst[i] = z[(size_t)(bb + bz) * (NT * NF) + (size_t)(NT - NP + t + 1) * NF + f];
                }
            }
        }

        // previous-step scalar output (recurrent input): reduce 16 partials
        float op = bo_s;
        #pragma unroll
        for (int r = 0; r < NRG; ++r) op += s_op[r][bl];
        const float inp0 = (t == 0) ? xlast : op;
        if (rg == 0 && t > 0) s_ob[t - 1][bl] = op;

        float acc[4][NJ];
        #pragma unroll
        for (int g = 0; g < 4; ++g)
            #pragma unroll
            for (int jj = 0; jj < NJ; ++jj) acc[g][jj] = bias[g][jj];

        // --- hh part: gates += h @ W_hh.T ---
        #pragma unroll 2
        for (int k4 = 0; k4 < NH / 4; ++k4) {
            float a0 = s_h[k4 * 4 + 0][bl];
            float a1 = s_h[k4 * 4 + 1][bl];
            float a2 = s_h[k4 * 4 + 2][bl];
            float a3 = s_h[k4 * 4 + 3][bl];
            fma4(acc, Whh, NH, k4 * 4, j0, a0, a1, a2, a3);
        }
        // --- ih part: inp = [out_prev, z0..z62] ---
        fma4(acc, Wih, 64, 0, j0, inp0, s_z[bl][0], s_z[bl][1], s_z[bl][2]);
        #pragma unroll 2
        for (int k4 = 1; k4 < 16; ++k4) {
            float a0 = s_z[bl][k4 * 4 - 1];
            float a1 = s_z[bl][k4 * 4 + 0];
            float a2 = s_z[bl][k4 * 4 + 1];
            float a3 = s_z[bl][k4 * 4 + 2];
            fma4(acc, Wih, 64, k4 * 4, j0, a0, a1, a2, a3);
        }

        // activations + state update
        #pragma unroll
        for (int jj = 0; jj < NJ; ++jj) {
            float gi = sig_(acc[0][jj]);
            float gf = sig_(acc[1][jj]);
            float gg = tanh_(acc[2][jj]);
            float go = sig_(acc[3][jj]);
            float cn = fmaf(gf, creg[jj], gi * gg);
            creg[jj] = cn;
            hreg[jj] = go * tanh_(cn);
        }

        __syncthreads();   // everyone done reading s_h / s_z / s_op

        {
            float op2 = 0.f;
            #pragma unroll
            for (int jj = 0; jj < NJ; ++jj) {
                s_h[j0 + jj][bl] = hreg[jj];
                op2 = fmaf(wo[jj], hreg[jj], op2);
            }
            s_op[rg][bl] = op2;
        }
        if (t < NP - 1) {
            #pragma unroll
            for (int i = 0; i < 4; ++i) {
                int idx = i * NTHREADS + tid;
                if (idx < BB * NF) {
                    int bz = idx / NF, f = idx - bz * NF;
                    s_z[bz][f] = zst[i];
                }
            }
        }
        __syncthreads();   // new h / z visible
    }

    // final step's output
    if (rg == 0) {
        float op = bo_s;
        #pragma unroll
        for (int r = 0; r < NRG; ++r) op += s_op[r][bl];
        s_ob[NP - 1][bl] = op;
    }
    __syncthreads();

    // flush outputs: d_out[b][t], coalesced float4 per thread
    {
        const int bo = tid >> 4, tq = tid & 15;
        float4 v;
        v.x = s_ob[tq * 4 + 0][bo];
        v.y = s_ob[tq * 4 + 1][bo];
        v.z = s_ob[tq * 4 + 2][bo];
        v.w = s_ob[tq * 4 + 3][bo];
        *reinterpret_cast<float4*>(&out[(size_t)(bb + bo) * NP + tq * 4]) = v;
    }
}

extern "C" void kernel_launch(void* const* d_in, const int* in_sizes, int n_in,
                              void* d_out, int out_size, void* d_ws, size_t ws_size,
                              hipStream_t stream) {
    const float* x    = (const float*)d_in[0];
    const float* z    = (const float*)d_in[1];
    const float* h0   = (const float*)d_in[2];
    const float* c0   = (const float*)d_in[3];
    const float* Wih  = (const float*)d_in[4];
    const float* Whh  = (const float*)d_in[5];
    const float* bih  = (const float*)d_in[6];
    const float* bhh  = (const float*)d_in[7];
    const float* Wout = (const float*)d_in[8];
    const float* bout = (const float*)d_in[9];
    float* out = (float*)d_out;

    lstm_fused<<<dim3(NB / BB), dim3(NTHREADS), 0, stream>>>(
        x, z, h0, c0, Wih, Whh, bih, bhh, Wout, bout, out);
}

// Round 4
// 2962.936 us; speedup vs baseline: 2.6452x; 2.6452x over previous
//
#include <hip/hip_runtime.h>

// LSTM decoder, register-stationary weights.
// B=8192, T=128, F=63, H=128, P=64 steps.
// 256 blocks x 512 threads. Block = 32 batch rows.
// Thread (j = tid>>2 in 0..127, kq = tid&3) owns gate rows {g*128+j, g=0..3}
// x k-columns [kq*48, kq*48+48) of W = 192 floats, held in VGPRs for all 64 steps.
// inp[b][k] (k: 0=out_prev, 1..63=z_t, 64..191=h) in double-buffered LDS.

#define NB 8192
#define NT 128
#define NF 63
#define NH 128
#define NP 64
#define BB 32
#define KS 48
#define NTHREADS 512

__device__ __forceinline__ float sig_(float v){ return 1.0f/(1.0f+__expf(-v)); }
__device__ __forceinline__ float tanh_(float v){
  float e=__expf(-2.0f*fabsf(v)); float t=(1.0f-e)/(1.0f+e); return copysignf(t,v);
}

__global__ __launch_bounds__(NTHREADS, 2)
void lstm_regw(const float* __restrict__ x, const float* __restrict__ z,
               const float* __restrict__ h0, const float* __restrict__ c0,
               const float* __restrict__ Wih, const float* __restrict__ Whh,
               const float* __restrict__ bih, const float* __restrict__ bhh,
               const float* __restrict__ Wout, const float* __restrict__ bout,
               float* __restrict__ out)
{
  const int tid  = threadIdx.x;
  const int kq   = tid & 3;        // k-slice 0..3
  const int j    = tid >> 2;       // 0..127
  const int lane = tid & 63;
  const int wv   = tid >> 6;       // wave 0..7
  const int bb   = blockIdx.x * BB;

  __shared__ float s_inp[2][BB][192];   // [buf][b][k]
  __shared__ float s_wp[BB][9];         // per-wave out partials (padded)
  __shared__ float s_ob[NP][BB+1];      // staged outputs (padded)

  // ---- weights -> registers (once). k<64: Wih col k; k>=64: Whh col k-64.
  // quads never straddle the 64 boundary (48/52/56/60 then 64).
  float4 w4[4][12];
  #pragma unroll
  for (int g=0; g<4; ++g){
    #pragma unroll
    for (int q=0; q<12; ++q){
      const int k = kq*KS + q*4;
      const int n = g*NH + j;
      w4[g][q] = (k < 64)
        ? *reinterpret_cast<const float4*>(&Wih[(size_t)n*64 + k])
        : *reinterpret_cast<const float4*>(&Whh[(size_t)n*NH + (k-64)]);
    }
  }
  const float wo  = Wout[j];
  const float bos = bout[0];
  float bias[4];
  #pragma unroll
  for (int g=0; g<4; ++g) bias[g] = bih[g*NH+j] + bhh[g*NH+j];

  // c state: this thread (lane kq) owns batch rows b = kq*8 + bi
  float creg[8];
  #pragma unroll
  for (int bi=0; bi<8; ++bi)
    creg[bi] = c0[(size_t)(bb + kq*8 + bi)*NH + j];

  // ---- prologue staging: h0, z(t=0), x_last
  #pragma unroll
  for (int i=0;i<8;++i){ int idx=i*NTHREADS+tid; int b=idx>>7, jj=idx&127;
    s_inp[0][b][64+jj] = h0[(size_t)(bb+b)*NH + jj]; }
  #pragma unroll
  for (int i=0;i<4;++i){ int idx=i*NTHREADS+tid; if(idx<BB*NF){ int b=idx/NF, f=idx-b*NF;
    s_inp[0][b][1+f] = z[(size_t)(bb+b)*(NT*NF) + (size_t)(NT-NP)*NF + f]; } }
  if (tid < BB) s_inp[0][tid][0] = x[(size_t)(bb+tid)*NT + (NT-1)];
  __syncthreads();

  int cur = 0;
  #pragma unroll 1
  for (int t=0; t<NP; ++t){
    const int nxt = cur ^ 1;

    // early z(t+1) global loads (latency hides under the b-loop)
    float zst[4] = {0.f,0.f,0.f,0.f};
    if (t < NP-1){
      #pragma unroll
      for (int i=0;i<4;++i){ int idx=i*NTHREADS+tid; if(idx<BB*NF){ int b=idx/NF, f=idx-b*NF;
        zst[i] = z[(size_t)(bb+b)*(NT*NF) + (size_t)(NT-NP+t+1)*NF + f]; } }
    }

    #pragma unroll 1
    for (int bo=0; bo<4; ++bo){
      #pragma unroll
      for (int bi=0; bi<8; ++bi){
        const int b = bo*8 + bi;
        const float4* ip4 = reinterpret_cast<const float4*>(&s_inp[cur][b][kq*KS]);
        float a0=0.f, a1=0.f, a2=0.f, a3=0.f;
        #pragma unroll
        for (int q=0; q<12; ++q){
          const float4 iv = ip4[q];   // 16-lane broadcast read, 2-way bank alias max
          a0=fmaf(w4[0][q].x,iv.x,a0); a0=fmaf(w4[0][q].y,iv.y,a0);
          a0=fmaf(w4[0][q].z,iv.z,a0); a0=fmaf(w4[0][q].w,iv.w,a0);
          a1=fmaf(w4[1][q].x,iv.x,a1); a1=fmaf(w4[1][q].y,iv.y,a1);
          a1=fmaf(w4[1][q].z,iv.z,a1); a1=fmaf(w4[1][q].w,iv.w,a1);
          a2=fmaf(w4[2][q].x,iv.x,a2); a2=fmaf(w4[2][q].y,iv.y,a2);
          a2=fmaf(w4[2][q].z,iv.z,a2); a2=fmaf(w4[2][q].w,iv.w,a2);
          a3=fmaf(w4[3][q].x,iv.x,a3); a3=fmaf(w4[3][q].y,iv.y,a3);
          a3=fmaf(w4[3][q].z,iv.z,a3); a3=fmaf(w4[3][q].w,iv.w,a3);
        }
        // k-reduction across the kq quad
        a0 += __shfl_xor(a0,1); a0 += __shfl_xor(a0,2);
        a1 += __shfl_xor(a1,1); a1 += __shfl_xor(a1,2);
        a2 += __shfl_xor(a2,1); a2 += __shfl_xor(a2,2);
        a3 += __shfl_xor(a3,1); a3 += __shfl_xor(a3,2);
        // gates + state (all lanes compute h; c broadcast from owning lane)
        const float gi = sig_(a0 + bias[0]);
        const float gf = sig_(a1 + bias[1]);
        const float gg = tanh_(a2 + bias[2]);
        const float go = sig_(a3 + bias[3]);
        const float cprev = __shfl(creg[bi], (lane & ~3) | bo);
        const float cn = fmaf(gf, cprev, gi*gg);
        const float h  = go * tanh_(cn);
        if (bo == kq) creg[bi] = cn;
        if (bo == kq) s_inp[nxt][b][64+j] = h;   // 16 lanes, distinct banks
        // scalar out feedback: p = wo*h, reduce over the 16 j's in this wave
        float p = wo * h;
        p += __shfl_xor(p,4);  p += __shfl_xor(p,8);
        p += __shfl_xor(p,16); p += __shfl_xor(p,32);
        if (lane == ((2*b)&63)) s_wp[b][wv] = p;
      }
    }

    // z(t+1) -> next buffer (region untouched by current readers)
    if (t < NP-1){
      #pragma unroll
      for (int i=0;i<4;++i){ int idx=i*NTHREADS+tid; if(idx<BB*NF){ int b=idx/NF, f=idx-b*NF;
        s_inp[nxt][b][1+f] = zst[i]; } }
    }
    __syncthreads();                 // s_wp + h writes visible
    if (tid < BB){
      float o = bos;
      #pragma unroll
      for (int w=0; w<8; ++w) o += s_wp[tid][w];
      s_ob[t][tid] = o;              // outs[t]
      s_inp[nxt][tid][0] = o;        // out feedback for step t+1
    }
    cur = nxt;
    __syncthreads();                 // next inp fully ready
  }

  // flush outputs: out[b][t], one float4 per thread
  {
    const int bo_ = tid >> 4, tq = tid & 15;
    float4 v;
    v.x = s_ob[tq*4+0][bo_];
    v.y = s_ob[tq*4+1][bo_];
    v.z = s_ob[tq*4+2][bo_];
    v.w = s_ob[tq*4+3][bo_];
    *reinterpret_cast<float4*>(&out[(size_t)(bb+bo_)*NP + tq*4]) = v;
  }
}

extern "C" void kernel_launch(void* const* d_in, const int* in_sizes, int n_in,
                              void* d_out, int out_size, void* d_ws, size_t ws_size,
                              hipStream_t stream) {
  const float* x    = (const float*)d_in[0];
  const float* z    = (const float*)d_in[1];
  const float* h0   = (const float*)d_in[2];
  const float* c0   = (const float*)d_in[3];
  const float* Wih  = (const float*)d_in[4];
  const float* Whh  = (const float*)d_in[5];
  const float* bih  = (const float*)d_in[6];
  const float* bhh  = (const float*)d_in[7];
  const float* Wout = (const float*)d_in[8];
  const float* bout = (const float*)d_in[9];
  float* out = (float*)d_out;

  lstm_regw<<<dim3(NB / BB), dim3(NTHREADS), 0, stream>>>(
      x, z, h0, c0, Wih, Whh, bih, bhh, Wout, bout, out);
}

// Round 5
// 1936.240 us; speedup vs baseline: 4.0478x; 1.5303x over previous
//
#include <hip/hip_runtime.h>

// LSTM decoder, register-stationary weights (pinned), gate-select activations.
// B=8192, T=128, F=63, H=128, P=64 steps.
// 256 blocks x 512 threads. Block = 32 batch rows.
// Thread (j = tid>>2, kq = tid&3) owns gate rows {g*128+j} x k-cols [kq*48, kq*48+48).
// 192 weight floats pinned in VGPRs via asm. inp[b][k] double-buffered in LDS
// (k: 0=out_prev, 1..63=z_t, 64..191=h). c state in LDS (thread-owned slots).

#define NB 8192
#define NT 128
#define NF 63
#define NH 128
#define NP 64
#define BB 32
#define KS 48
#define NTHREADS 512

#if __has_builtin(__builtin_amdgcn_rcpf)
#define RCP_(x) __builtin_amdgcn_rcpf(x)
#else
#define RCP_(x) (1.0f/(x))
#endif

__device__ __forceinline__ float sig_(float v){
  return RCP_(1.0f + __expf(-v));
}
__device__ __forceinline__ float tanh_(float v){
  float e = __expf(-2.0f*fabsf(v));
  float t = (1.0f - e) * RCP_(1.0f + e);
  return copysignf(t, v);
}

__global__ __launch_bounds__(NTHREADS, 2)
void lstm_regw2(const float* __restrict__ x, const float* __restrict__ z,
                const float* __restrict__ h0, const float* __restrict__ c0,
                const float* __restrict__ Wih, const float* __restrict__ Whh,
                const float* __restrict__ bih, const float* __restrict__ bhh,
                const float* __restrict__ Wout, const float* __restrict__ bout,
                float* __restrict__ out)
{
  const int tid  = threadIdx.x;
  const int kq   = tid & 3;        // k-slice 0..3
  const int j    = tid >> 2;       // 0..127
  const int lane = tid & 63;
  const int wv   = tid >> 6;       // wave 0..7
  const int bb   = blockIdx.x * BB;

  __shared__ float s_inp[2][BB][192];   // [buf][b][k]
  __shared__ float s_c[BB][NH];         // c state, slot (b,j) owned by one thread
  __shared__ float s_wp[BB][9];         // per-wave out partials (padded)
  __shared__ float s_ob[NP][BB + 1];    // staged outputs (padded)

  // ---- weights -> registers (once). k<64: Wih col k; k>=64: Whh col k-64.
  float4 w4[4][12];
  #pragma unroll
  for (int g = 0; g < 4; ++g){
    #pragma unroll
    for (int q = 0; q < 12; ++q){
      const int k = kq*KS + q*4;
      const int n = g*NH + j;
      w4[g][q] = (k < 64)
        ? *reinterpret_cast<const float4*>(&Wih[(size_t)n*64 + k])
        : *reinterpret_cast<const float4*>(&Whh[(size_t)n*NH + (k-64)]);
    }
  }
  // Pin: asm "+v" redefines each value -> cannot be rematerialized from the
  // load inside the loop; must stay register-resident (VGPR_Count should ~240).
  #pragma unroll
  for (int g = 0; g < 4; ++g)
    #pragma unroll
    for (int q = 0; q < 12; ++q)
      asm volatile("" : "+v"(w4[g][q].x), "+v"(w4[g][q].y),
                        "+v"(w4[g][q].z), "+v"(w4[g][q].w));

  const float wo  = Wout[j];
  const float bos = bout[0];
  float bias[4];
  #pragma unroll
  for (int g = 0; g < 4; ++g) bias[g] = bih[g*NH + j] + bhh[g*NH + j];

  // ---- prologue staging: h0 -> s_inp, c0 -> s_c, z(t=0), x_last
  #pragma unroll
  for (int i = 0; i < 8; ++i){ int idx = i*NTHREADS + tid; int b = idx >> 7, jj = idx & 127;
    s_inp[0][b][64 + jj] = h0[(size_t)(bb + b)*NH + jj];
    s_c[b][jj]           = c0[(size_t)(bb + b)*NH + jj]; }
  #pragma unroll
  for (int i = 0; i < 4; ++i){ int idx = i*NTHREADS + tid; if (idx < BB*NF){ int b = idx/NF, f = idx - b*NF;
    s_inp[0][b][1 + f] = z[(size_t)(bb + b)*(NT*NF) + (size_t)(NT - NP)*NF + f]; } }
  if (tid < BB) s_inp[0][tid][0] = x[(size_t)(bb + tid)*NT + (NT - 1)];
  __syncthreads();

  int cur = 0;
  #pragma unroll 1
  for (int t = 0; t < NP; ++t){
    const int nxt = cur ^ 1;

    // early z(t+1) global loads (latency hides under the bi-loop)
    float zst[4] = {0.f, 0.f, 0.f, 0.f};
    if (t < NP - 1){
      #pragma unroll
      for (int i = 0; i < 4; ++i){ int idx = i*NTHREADS + tid; if (idx < BB*NF){ int b = idx/NF, f = idx - b*NF;
        zst[i] = z[(size_t)(bb + b)*(NT*NF) + (size_t)(NT - NP + t + 1)*NF + f]; } }
    }

    #pragma unroll 1
    for (int bi = 0; bi < 8; ++bi){
      // one LDS base; (bo,q) resolve to compile-time ds_read offsets
      const float4* ip4 = reinterpret_cast<const float4*>(&s_inp[cur][bi][kq*KS]);
      float ag[4] = {0.f, 0.f, 0.f, 0.f};
      #pragma unroll
      for (int bo = 0; bo < 4; ++bo){
        float a0 = 0.f, a1 = 0.f, a2 = 0.f, a3 = 0.f;
        #pragma unroll
        for (int q = 0; q < 12; ++q){
          const float4 iv = ip4[bo*384 + q];   // b = bo*8+bi, 16-lane broadcast
          a0 = fmaf(w4[0][q].x, iv.x, a0); a0 = fmaf(w4[0][q].y, iv.y, a0);
          a0 = fmaf(w4[0][q].z, iv.z, a0); a0 = fmaf(w4[0][q].w, iv.w, a0);
          a1 = fmaf(w4[1][q].x, iv.x, a1); a1 = fmaf(w4[1][q].y, iv.y, a1);
          a1 = fmaf(w4[1][q].z, iv.z, a1); a1 = fmaf(w4[1][q].w, iv.w, a1);
          a2 = fmaf(w4[2][q].x, iv.x, a2); a2 = fmaf(w4[2][q].y, iv.y, a2);
          a2 = fmaf(w4[2][q].z, iv.z, a2); a2 = fmaf(w4[2][q].w, iv.w, a2);
          a3 = fmaf(w4[3][q].x, iv.x, a3); a3 = fmaf(w4[3][q].y, iv.y, a3);
          a3 = fmaf(w4[3][q].z, iv.z, a3); a3 = fmaf(w4[3][q].w, iv.w, a3);
        }
        // k-reduction across the quad
        a0 += __shfl_xor(a0, 1); a0 += __shfl_xor(a0, 2);
        a1 += __shfl_xor(a1, 1); a1 += __shfl_xor(a1, 2);
        a2 += __shfl_xor(a2, 1); a2 += __shfl_xor(a2, 2);
        a3 += __shfl_xor(a3, 1); a3 += __shfl_xor(a3, 2);
        // keep own row's gates (lane kq owns b = kq*8+bi)
        if (kq == bo){ ag[0] = a0; ag[1] = a1; ag[2] = a2; ag[3] = a3; }
      }
      // activations ONCE per 4 rows (each lane on its own row; no redundancy)
      const int bown = kq*8 + bi;
      const float cprev = s_c[bown][j];
      const float gi = sig_ (ag[0] + bias[0]);
      const float gf = sig_ (ag[1] + bias[1]);
      const float gg = tanh_(ag[2] + bias[2]);
      const float go = sig_ (ag[3] + bias[3]);
      const float cn = fmaf(gf, cprev, gi*gg);
      const float h  = go * tanh_(cn);
      s_c[bown][j] = cn;                 // thread-owned slot, no race
      s_inp[nxt][bown][64 + j] = h;      // next-step input
      // scalar out feedback: sum wo*h over the wave's 16 j's per row
      float p = wo * h;
      p += __shfl_xor(p, 4);  p += __shfl_xor(p, 8);
      p += __shfl_xor(p, 16); p += __shfl_xor(p, 32);
      if (lane < 4) s_wp[bown][wv] = p;  // lanes 0..3 carry kq = 0..3
    }

    // z(t+1) -> next buffer (disjoint from h/out regions)
    if (t < NP - 1){
      #pragma unroll
      for (int i = 0; i < 4; ++i){ int idx = i*NTHREADS + tid; if (idx < BB*NF){ int b = idx/NF, f = idx - b*NF;
        s_inp[nxt][b][1 + f] = zst[i]; } }
    }
    __syncthreads();                 // s_wp + h writes visible
    if (tid < BB){
      float o = bos;
      #pragma unroll
      for (int w = 0; w < 8; ++w) o += s_wp[tid][w];
      s_ob[t][tid] = o;              // outs[t]
      s_inp[nxt][tid][0] = o;        // out feedback for step t+1
    }
    cur = nxt;
    __syncthreads();                 // next inp fully ready
  }

  // flush outputs: out[b][t], one float4 per thread
  {
    const int bo_ = tid >> 4, tq = tid & 15;
    float4 v;
    v.x = s_ob[tq*4 + 0][bo_];
    v.y = s_ob[tq*4 + 1][bo_];
    v.z = s_ob[tq*4 + 2][bo_];
    v.w = s_ob[tq*4 + 3][bo_];
    *reinterpret_cast<float4*>(&out[(size_t)(bb + bo_)*NP + tq*4]) = v;
  }
}

extern "C" void kernel_launch(void* const* d_in, const int* in_sizes, int n_in,
                              void* d_out, int out_size, void* d_ws, size_t ws_size,
                              hipStream_t stream) {
  const float* x    = (const float*)d_in[0];
  const float* z    = (const float*)d_in[1];
  const float* h0   = (const float*)d_in[2];
  const float* c0   = (const float*)d_in[3];
  const float* Wih  = (const float*)d_in[4];
  const float* Whh  = (const float*)d_in[5];
  const float* bih  = (const float*)d_in[6];
  const float* bhh  = (const float*)d_in[7];
  const float* Wout = (const float*)d_in[8];
  const float* bout = (const float*)d_in[9];
  float* out = (float*)d_out;

  lstm_regw2<<<dim3(NB / BB), dim3(NTHREADS), 0, stream>>>(
      x, z, h0, c0, Wih, Whh, bih, bhh, Wout, bout, out);
}

// Round 6
// 445.811 us; speedup vs baseline: 17.5806x; 4.3432x over previous
//
#include <hip/hip_runtime.h>

// LSTM decoder via fp16 MFMA. B=8192, T=128, F=63, H=128, P=64 steps.
// 256 blocks x 512 threads (8 waves). Block = 32 batch rows.
// Per step: gates D[512n][32b] = W[512x192] x inp^T[192x32] via
// mfma_f32_16x16x32_f16. Wave w owns n-tiles {w+8g, g=0..3} x 2 b-tiles ->
// each lane holds ALL 4 gates of its 8 (b,j) cells -> in-register activations.
// Weights fp16 in 96 regs/thread (VGPR or AGPR - MFMA reads both). inp
// (out_prev | z_t | h) fp16 in double-buffered LDS, pitch 200 (bank-uniform).

#define NB 8192
#define NT 128
#define NF 63
#define NH 128
#define NP 64
#define BB 32
#define NTHREADS 512

typedef _Float16 f16;
typedef _Float16 f16x8 __attribute__((ext_vector_type(8)));
typedef _Float16 f16x4 __attribute__((ext_vector_type(4)));
typedef float    f32x4 __attribute__((ext_vector_type(4)));

#if __has_builtin(__builtin_amdgcn_rcpf)
#define RCP_(x) __builtin_amdgcn_rcpf(x)
#else
#define RCP_(x) (1.0f/(x))
#endif

__device__ __forceinline__ float sig_(float v){
  return RCP_(1.0f + __expf(-v));
}
__device__ __forceinline__ float tanh_(float v){
  float e = __expf(-2.0f*fabsf(v));
  return copysignf((1.0f - e)*RCP_(1.0f + e), v);
}

__global__ __launch_bounds__(NTHREADS)
__attribute__((amdgpu_waves_per_eu(2, 2)))
void lstm_mfma(const float* __restrict__ x, const float* __restrict__ z,
               const float* __restrict__ h0, const float* __restrict__ c0,
               const float* __restrict__ Wih, const float* __restrict__ Whh,
               const float* __restrict__ bih, const float* __restrict__ bhh,
               const float* __restrict__ Wout, const float* __restrict__ bout,
               float* __restrict__ out)
{
  const int tid  = threadIdx.x;
  const int lane = tid & 63;
  const int wv   = tid >> 6;       // wave 0..7
  const int lh   = lane & 15;
  const int lq   = lane >> 4;      // 0..3
  const int bb   = blockIdx.x * BB;
  const int j0   = wv*16 + lq*4;   // lane's 4 consecutive j (C-frag rows)

  __shared__ __align__(16) f16 s_inp[2][BB][200];  // [buf][b][k], k:0=out,1..63=z,64..191=h
  __shared__ float s_wp[BB][9];                    // per-wave out partials
  __shared__ float s_ob[NP][BB + 1];               // staged outputs

  // ---- A-fragments (weights), fp16, loaded once.
  // A-tile for (g,kt): rows n = g*128 + wv*16 + (lane&15), k = kt*32 + lq*8 + e.
  f16x8 afr[4][6];
  #pragma unroll
  for (int g = 0; g < 4; ++g){
    const int n = g*NH + wv*16 + lh;
    #pragma unroll
    for (int kt = 0; kt < 6; ++kt){
      const float* wp = (kt < 2)
        ? &Wih[(size_t)n*64 + kt*32 + lq*8]
        : &Whh[(size_t)n*NH + (kt - 2)*32 + lq*8];
      const float4 wa = *reinterpret_cast<const float4*>(wp);
      const float4 wb = *reinterpret_cast<const float4*>(wp + 4);
      f16x8 tf;
      tf[0] = (f16)wa.x; tf[1] = (f16)wa.y; tf[2] = (f16)wa.z; tf[3] = (f16)wa.w;
      tf[4] = (f16)wb.x; tf[5] = (f16)wb.y; tf[6] = (f16)wb.z; tf[7] = (f16)wb.w;
      afr[g][kt] = tf;
    }
  }

  // biases / W_out slices for this lane's j0..j0+3 (f32 precision kept)
  f32x4 bias4[4];
  #pragma unroll
  for (int g = 0; g < 4; ++g){
    const float4 a  = *reinterpret_cast<const float4*>(&bih[g*NH + j0]);
    const float4 b2 = *reinterpret_cast<const float4*>(&bhh[g*NH + j0]);
    bias4[g][0] = a.x + b2.x; bias4[g][1] = a.y + b2.y;
    bias4[g][2] = a.z + b2.z; bias4[g][3] = a.w + b2.w;
  }
  const float4 wo4 = *reinterpret_cast<const float4*>(&Wout[j0]);
  const float  bos = bout[0];

  // c state: lane owns cells (b = bt*16+lh, j = j0+i), f32 in regs
  f32x4 creg[2];
  #pragma unroll
  for (int bt = 0; bt < 2; ++bt){
    const float4 c4 = *reinterpret_cast<const float4*>(
        &c0[(size_t)(bb + bt*16 + lh)*NH + j0]);
    creg[bt][0] = c4.x; creg[bt][1] = c4.y; creg[bt][2] = c4.z; creg[bt][3] = c4.w;
  }

  // ---- prologue staging: h0, z(t=0), x_last (all -> fp16 LDS)
  #pragma unroll
  for (int i = 0; i < 8; ++i){ int idx = i*NTHREADS + tid; int b = idx >> 7, jj = idx & 127;
    s_inp[0][b][64 + jj] = (f16)h0[(size_t)(bb + b)*NH + jj]; }
  #pragma unroll
  for (int i = 0; i < 4; ++i){ int idx = i*NTHREADS + tid; if (idx < BB*NF){ int b = idx/NF, f = idx - b*NF;
    s_inp[0][b][1 + f] = (f16)z[(size_t)(bb + b)*(NT*NF) + (size_t)(NT - NP)*NF + f]; } }
  if (tid < BB) s_inp[0][tid][0] = (f16)x[(size_t)(bb + tid)*NT + (NT - 1)];
  __syncthreads();

  int cur = 0;
  #pragma unroll 1
  for (int t = 0; t < NP; ++t){
    const int nxt = cur ^ 1;

    // early z(t+1) global loads (hide HBM latency under MFMA+activations)
    float zst[4] = {0.f, 0.f, 0.f, 0.f};
    if (t < NP - 1){
      #pragma unroll
      for (int i = 0; i < 4; ++i){ int idx = i*NTHREADS + tid; if (idx < BB*NF){ int b = idx/NF, f = idx - b*NF;
        zst[i] = z[(size_t)(bb + b)*(NT*NF) + (size_t)(NT - NP + t + 1)*NF + f]; } }
    }

    // ---- gates = bias + W x inp^T  (bias preloaded into accumulator)
    f32x4 acc[4][2];
    #pragma unroll
    for (int g = 0; g < 4; ++g){ acc[g][0] = bias4[g]; acc[g][1] = bias4[g]; }

    #pragma unroll
    for (int kt = 0; kt < 6; ++kt){
      // B-frag: lane holds inp[b = bt*16 + (lane&15)][kt*32 + lq*8 + e]
      const f16x8 b0 = *reinterpret_cast<const f16x8*>(&s_inp[cur][lh     ][kt*32 + lq*8]);
      const f16x8 b1 = *reinterpret_cast<const f16x8*>(&s_inp[cur][16 + lh][kt*32 + lq*8]);
      #pragma unroll
      for (int g = 0; g < 4; ++g){
        acc[g][0] = __builtin_amdgcn_mfma_f32_16x16x32_f16(afr[g][kt], b0, acc[g][0], 0, 0, 0);
        acc[g][1] = __builtin_amdgcn_mfma_f32_16x16x32_f16(afr[g][kt], b1, acc[g][1], 0, 0, 0);
      }
    }

    // ---- activations fully in-register (lane owns all 4 gates of its cells)
    float p0, p1;
    {
      float hv0[4], hv1[4];
      #pragma unroll
      for (int i = 0; i < 4; ++i){
        const float gi = sig_ (acc[0][0][i]);
        const float gf = sig_ (acc[1][0][i]);
        const float gg = tanh_(acc[2][0][i]);
        const float go = sig_ (acc[3][0][i]);
        const float cn = fmaf(gf, creg[0][i], gi*gg);
        creg[0][i] = cn;
        hv0[i] = go * tanh_(cn);
      }
      #pragma unroll
      for (int i = 0; i < 4; ++i){
        const float gi = sig_ (acc[0][1][i]);
        const float gf = sig_ (acc[1][1][i]);
        const float gg = tanh_(acc[2][1][i]);
        const float go = sig_ (acc[3][1][i]);
        const float cn = fmaf(gf, creg[1][i], gi*gg);
        creg[1][i] = cn;
        hv1[i] = go * tanh_(cn);
      }
      f16x4 hq0, hq1;
      hq0[0] = (f16)hv0[0]; hq0[1] = (f16)hv0[1]; hq0[2] = (f16)hv0[2]; hq0[3] = (f16)hv0[3];
      hq1[0] = (f16)hv1[0]; hq1[1] = (f16)hv1[1]; hq1[2] = (f16)hv1[2]; hq1[3] = (f16)hv1[3];
      *reinterpret_cast<f16x4*>(&s_inp[nxt][lh     ][64 + j0]) = hq0;   // b64 write, 4 h
      *reinterpret_cast<f16x4*>(&s_inp[nxt][16 + lh][64 + j0]) = hq1;
      p0 = (hv0[0]*wo4.x + hv0[1]*wo4.y) + (hv0[2]*wo4.z + hv0[3]*wo4.w);
      p1 = (hv1[0]*wo4.x + hv1[1]*wo4.y) + (hv1[2]*wo4.z + hv1[3]*wo4.w);
    }
    // reduce over lq within wave (lanes lh, lh^16, lh^32, lh^48)
    p0 += __shfl_xor(p0, 16); p0 += __shfl_xor(p0, 32);
    p1 += __shfl_xor(p1, 16); p1 += __shfl_xor(p1, 32);
    if (lq == 0){ s_wp[lh][wv] = p0; s_wp[16 + lh][wv] = p1; }

    // z(t+1) -> next buffer (disjoint from h/out regions)
    if (t < NP - 1){
      #pragma unroll
      for (int i = 0; i < 4; ++i){ int idx = i*NTHREADS + tid; if (idx < BB*NF){ int b = idx/NF, f = idx - b*NF;
        s_inp[nxt][b][1 + f] = (f16)zst[i]; } }
    }
    __syncthreads();                 // h, s_wp, z visible
    if (tid < BB){
      float o = bos;
      #pragma unroll
      for (int w = 0; w < 8; ++w) o += s_wp[tid][w];
      s_ob[t][tid] = o;              // outs[t]
      s_inp[nxt][tid][0] = (f16)o;   // out feedback for step t+1
    }
    cur = nxt;
    __syncthreads();                 // next inp fully ready
  }

  // flush outputs: out[b][t], one float4 per thread
  {
    const int bo_ = tid >> 4, tq = tid & 15;
    float4 v;
    v.x = s_ob[tq*4 + 0][bo_];
    v.y = s_ob[tq*4 + 1][bo_];
    v.z = s_ob[tq*4 + 2][bo_];
    v.w = s_ob[tq*4 + 3][bo_];
    *reinterpret_cast<float4*>(&out[(size_t)(bb + bo_)*NP + tq*4]) = v;
  }
}

extern "C" void kernel_launch(void* const* d_in, const int* in_sizes, int n_in,
                              void* d_out, int out_size, void* d_ws, size_t ws_size,
                              hipStream_t stream) {
  const float* x    = (const float*)d_in[0];
  const float* z    = (const float*)d_in[1];
  const float* h0   = (const float*)d_in[2];
  const float* c0   = (const float*)d_in[3];
  const float* Wih  = (const float*)d_in[4];
  const float* Whh  = (const float*)d_in[5];
  const float* bih  = (const float*)d_in[6];
  const float* bhh  = (const float*)d_in[7];
  const float* Wout = (const float*)d_in[8];
  const float* bout = (const float*)d_in[9];
  float* out = (float*)d_out;

  lstm_mfma<<<dim3(NB / BB), dim3(NTHREADS), 0, stream>>>(
      x, z, h0, c0, Wih, Whh, bih, bhh, Wout, bout, out);
}